// Round 5
// baseline (308.033 us; speedup 1.0000x reference)
//
#include <hip/hip_runtime.h>

// PersonaGNN: 2-layer GAT, N=100000, E=600000 (+self loops), dims 128, fp32 io.
//
// R5: register-resident-W MFMA GEMM.
//  - prep_w packs W1/W2 into fragment-ordered bf16 (coalesced dwordx4 frag loads).
//  - gemm_mfma v3: NO LDS, NO barriers. Each wave holds all 32 W-frags in
//    VGPRs (128 regs), grid-strides over 16-row X tiles with register
//    double-buffered X loads. Grid=512 blocks = exactly-resident 2048 waves.
//    (R4 failure mode: 6.3M LDS bank conflicts in W staging + 8.8% occupancy.)
//  - gat_agg2 / CSR build unchanged from R4.

#define NEG_SLOPE 0.2f

typedef __attribute__((ext_vector_type(8))) short bf16x8;
typedef __attribute__((ext_vector_type(4))) float f32x4;

__device__ __forceinline__ float leaky(float x) { return x > 0.0f ? x : NEG_SLOPE * x; }

__device__ __forceinline__ unsigned int bf16rne(float f) {
  unsigned int u = __float_as_uint(f);
  return (u + 0x7fffu + ((u >> 16) & 1u)) >> 16;
}
__device__ __forceinline__ unsigned int packbf(float a, float b) {
  return bf16rne(a) | (bf16rne(b) << 16);
}
__device__ __forceinline__ float bf_lo(unsigned int u) { return __uint_as_float(u << 16); }
__device__ __forceinline__ float bf_hi(unsigned int u) { return __uint_as_float(u & 0xffff0000u); }

__device__ __forceinline__ void accum8(float* a, float w, uint4 h) {
  a[0] += w * bf_lo(h.x); a[1] += w * bf_hi(h.x);
  a[2] += w * bf_lo(h.y); a[3] += w * bf_hi(h.y);
  a[4] += w * bf_lo(h.z); a[5] += w * bf_hi(h.z);
  a[6] += w * bf_lo(h.w); a[7] += w * bf_hi(h.w);
}

// ---------------- CSR build ----------------
__global__ void hist_kernel(const int* __restrict__ dst, int* __restrict__ deg, int E) {
  int e = blockIdx.x * 256 + threadIdx.x;
  if (e < E) atomicAdd(&deg[dst[e]], 1);
}

__global__ void scan_a(const int* __restrict__ cnt, int* __restrict__ exc,
                       int* __restrict__ bsum, int n) {
  __shared__ int sh[256];
  int b = blockIdx.x, tid = threadIdx.x;
  int base = b * 1024 + tid * 4;
  int v[4];
#pragma unroll
  for (int i = 0; i < 4; i++) v[i] = (base + i < n) ? cnt[base + i] : 0;
  int tsum = v[0] + v[1] + v[2] + v[3];
  sh[tid] = tsum;
  __syncthreads();
  for (int o = 1; o < 256; o <<= 1) {
    int t = (tid >= o) ? sh[tid - o] : 0;
    __syncthreads();
    sh[tid] += t;
    __syncthreads();
  }
  if (tid == 255) bsum[b] = sh[255];
  int run = sh[tid] - tsum;
#pragma unroll
  for (int i = 0; i < 4; i++) {
    if (base + i < n) exc[base + i] = run;
    run += v[i];
  }
}

__global__ void scan_c2(const int* __restrict__ exc, const int* __restrict__ bsum,
                        int* __restrict__ rowst, int* __restrict__ fill, int n, int E,
                        int nb) {
  __shared__ int red[256];
  int b = blockIdx.x, tid = threadIdx.x;
  red[tid] = (tid < b && tid < nb) ? bsum[tid] : 0;
  __syncthreads();
#pragma unroll
  for (int o = 128; o; o >>= 1) {
    if (tid < o) red[tid] += red[tid + o];
    __syncthreads();
  }
  int off = red[0];
  int base = b * 1024 + tid * 4;
#pragma unroll
  for (int i = 0; i < 4; i++) {
    int idx = base + i;
    if (idx < n) {
      int v = exc[idx] + off;
      rowst[idx] = v;
      fill[idx] = v;
    }
  }
  if (b == 0 && tid == 0) rowst[n] = E;
}

__global__ void scatter_kernel(const int* __restrict__ src, const int* __restrict__ dst,
                               int* __restrict__ fill, int* __restrict__ esrc, int E) {
  int e = blockIdx.x * 256 + threadIdx.x;
  if (e < E) {
    int v = dst[e];
    int p = atomicAdd(&fill[v], 1);
    esrc[p] = src[e];
  }
}

// -------- prep_w: pack W (fp32 [k][n]) into fragment-ordered bf16 ----------
// Wf[(ct*4+ks)*512 + lane*8 + j] = bf16(W[ks*32 + (lane>>4)*8 + j][ct*16 + (lane&15)])
__global__ void prep_w(const float* __restrict__ W1, const float* __restrict__ W2,
                       unsigned short* __restrict__ Wf1, unsigned short* __restrict__ Wf2) {
  const float* W = blockIdx.x ? W2 : W1;
  unsigned short* Wf = blockIdx.x ? Wf2 : Wf1;
  for (int idx = threadIdx.x; idx < 16384; idx += 256) {
    int j = idx & 7;
    int lane = (idx >> 3) & 63;
    int fid = idx >> 9;
    int ct = fid >> 2, ks = fid & 3;
    int q = lane >> 4, l15 = lane & 15;
    Wf[idx] = (unsigned short)bf16rne(W[(ks * 32 + q * 8 + j) * 128 + ct * 16 + l15]);
  }
}

// ------- MFMA GEMM v3: H[n,128](bf16) = X[n,128] @ W, + fused dots ----------
// No LDS, no barriers. 32 W-frags register-resident per wave; grid-stride over
// 16-row tiles with register double-buffered X loads.
template <bool F32IN>
__global__ __launch_bounds__(256, 2) void gemm_mfma(const void* __restrict__ Xin,
                                                    const unsigned short* __restrict__ Wf,
                                                    const float* __restrict__ a_s,
                                                    const float* __restrict__ a_d,
                                                    unsigned short* __restrict__ H,
                                                    float* __restrict__ vas,
                                                    float* __restrict__ vad, int n,
                                                    int nt16) {
  const int lane = threadIdx.x & 63;
  const int wv = threadIdx.x >> 6;
  const int l15 = lane & 15;
  const int q = lane >> 4;

  // load all 32 W fragments (coalesced dwordx4, L2-hot)
  bf16x8 wfrag[8][4];
#pragma unroll
  for (int ct = 0; ct < 8; ct++)
#pragma unroll
    for (int ks = 0; ks < 4; ks++)
      wfrag[ct][ks] = *(const bf16x8*)&Wf[(((ct << 2) + ks) << 9) + lane * 8];

  const float* __restrict__ Xf = (const float*)Xin;
  const unsigned short* __restrict__ Xh = (const unsigned short*)Xin;
  const int stride = gridDim.x * 4;
  int t = blockIdx.x * 4 + wv;
  if (t >= nt16) return;

  // raw X registers (double-buffered): fp32 path keeps raw float4s so the
  // prefetch issue isn't serialized behind the bf16 convert.
  float4 cf[8];
  bf16x8 cb[4];

  auto loadraw = [&](int tile, float4* f, bf16x8* b) {
    const int myrow = tile * 16 + l15;
    const bool act = myrow < n;
    if constexpr (F32IN) {
#pragma unroll
      for (int ks = 0; ks < 4; ks++) {
        float4 z = {0.f, 0.f, 0.f, 0.f};
        f[2 * ks] = z;
        f[2 * ks + 1] = z;
        if (act) {
          f[2 * ks] = *(const float4*)&Xf[(size_t)myrow * 128 + ks * 32 + q * 8];
          f[2 * ks + 1] = *(const float4*)&Xf[(size_t)myrow * 128 + ks * 32 + q * 8 + 4];
        }
      }
    } else {
#pragma unroll
      for (int ks = 0; ks < 4; ks++) {
        b[ks] = (bf16x8){0, 0, 0, 0, 0, 0, 0, 0};
        if (act) b[ks] = *(const bf16x8*)&Xh[(size_t)myrow * 128 + ks * 32 + q * 8];
      }
    }
  };

  loadraw(t, cf, cb);

  while (t < nt16) {
    const int tn = t + stride;
    float4 nf[8];
    bf16x8 nb[4];
    if (tn < nt16) loadraw(tn, nf, nb);

    // convert current tile to A/B frags
    bf16x8 xf[4];
    if constexpr (F32IN) {
#pragma unroll
      for (int ks = 0; ks < 4; ks++) {
        union { bf16x8 v; unsigned int u[4]; } cv;
        cv.u[0] = packbf(cf[2 * ks].x, cf[2 * ks].y);
        cv.u[1] = packbf(cf[2 * ks].z, cf[2 * ks].w);
        cv.u[2] = packbf(cf[2 * ks + 1].x, cf[2 * ks + 1].y);
        cv.u[3] = packbf(cf[2 * ks + 1].z, cf[2 * ks + 1].w);
        xf[ks] = cv.v;
      }
    } else {
#pragma unroll
      for (int ks = 0; ks < 4; ks++) xf[ks] = cb[ks];
    }

    f32x4 acc[8];
#pragma unroll
    for (int ct = 0; ct < 8; ct++) acc[ct] = (f32x4){0.f, 0.f, 0.f, 0.f};
#pragma unroll
    for (int ks = 0; ks < 4; ks++)
#pragma unroll
      for (int ct = 0; ct < 8; ct++)
        acc[ct] = __builtin_amdgcn_mfma_f32_16x16x32_bf16(wfrag[ct][ks], xf[ks], acc[ct], 0, 0, 0);

    // epilogue: lane holds H[myrow][ct*16 + q*4 + r], r=0..3
    const int myrow = t * 16 + l15;
    const bool act = myrow < n;
    float ds = 0.f, dd = 0.f;
#pragma unroll
    for (int ct = 0; ct < 8; ct++) {
      const int c0 = ct * 16 + q * 4;
      float4 as4 = *(const float4*)&a_s[c0];
      float4 ad4 = *(const float4*)&a_d[c0];
      ds += acc[ct][0] * as4.x + acc[ct][1] * as4.y + acc[ct][2] * as4.z + acc[ct][3] * as4.w;
      dd += acc[ct][0] * ad4.x + acc[ct][1] * ad4.y + acc[ct][2] * ad4.z + acc[ct][3] * ad4.w;
      if (act) {
        uint2 o;
        o.x = packbf(acc[ct][0], acc[ct][1]);
        o.y = packbf(acc[ct][2], acc[ct][3]);
        *(uint2*)&H[(size_t)myrow * 128 + c0] = o;
      }
    }
    ds += __shfl_xor(ds, 16, 64);
    ds += __shfl_xor(ds, 32, 64);
    dd += __shfl_xor(dd, 16, 64);
    dd += __shfl_xor(dd, 32, 64);
    if (q == 0 && act) {
      vas[myrow] = ds;
      vad[myrow] = dd;
    }

    // rotate prefetch buffers
    if constexpr (F32IN) {
#pragma unroll
      for (int i = 0; i < 8; i++) cf[i] = nf[i];
    } else {
#pragma unroll
      for (int i = 0; i < 4; i++) cb[i] = nb[i];
    }
    t = tn;
  }
}

// ---------------- GAT aggregation: 4 nodes per wave, 16 lanes/node ----------------
// LAYER==1: relu + bf16 node output.  LAYER==2: fused mean into partial[64][128].
template <int LAYER>
__global__ __launch_bounds__(256) void gat_agg2(const unsigned short* __restrict__ H,
                                                const float* __restrict__ vas,
                                                const float* __restrict__ vad,
                                                const int* __restrict__ rowst,
                                                const int* __restrict__ esrc,
                                                const float* __restrict__ bias,
                                                unsigned short* __restrict__ OutBf,
                                                float* __restrict__ partial, int n) {
  const int tid = threadIdx.x;
  const int lane = tid & 63;
  const int wv = tid >> 6;
  const int q = lane >> 4;
  const int l = lane & 15;
  const int node = (blockIdx.x * 4 + wv) * 4 + q;  // 16 nodes per block
  const uint4* __restrict__ H4 = (const uint4*)H;

  float acc[8];
#pragma unroll
  for (int k = 0; k < 8; k++) acc[k] = 0.f;

  if (node < n) {
    const int s = rowst[node];
    const int e = rowst[node + 1];
    const int deg = e - s;
    const float adv = vad[node];
    const float eself = leaky(vas[node] + adv);
    uint4 hs = H4[(size_t)node * 16 + l];
    float wself, dsum;

    if (deg <= 16) {
      int uj = 0;
      float ej = -1e30f;
      const bool a = l < deg;
      if (a) {
        uj = esrc[s + l];
        ej = leaky(vas[uj] + adv);
      }
      float m = fmaxf(eself, ej);
#pragma unroll
      for (int o = 8; o; o >>= 1) m = fmaxf(m, __shfl_xor(m, o, 16));
      float wj = a ? __expf(ej - m) : 0.f;
      wself = __expf(eself - m);
      dsum = wj;
#pragma unroll
      for (int o = 8; o; o >>= 1) dsum += __shfl_xor(dsum, o, 16);
#pragma unroll 1
      for (int t0 = 0; t0 < deg; t0 += 4) {
        const int tb = deg - t0;
        uint4 hb[4];
        float wt[4];
#pragma unroll
        for (int i = 0; i < 4; i++) {
          if (i < tb) {
            int ut = __shfl(uj, (lane & 48) + t0 + i, 64);
            wt[i] = __shfl(wj, (lane & 48) + t0 + i, 64);
            hb[i] = H4[(size_t)ut * 16 + l];
          }
        }
#pragma unroll
        for (int i = 0; i < 4; i++)
          if (i < tb) accum8(acc, wt[i], hb[i]);
      }
    } else {
      // generic (deg>16 is rare)
      float m = eself;
      for (int t0 = 0; t0 < deg; t0 += 16) {
        int j = t0 + l;
        if (j < deg) {
          int u = esrc[s + j];
          m = fmaxf(m, leaky(vas[u] + adv));
        }
      }
#pragma unroll
      for (int o = 8; o; o >>= 1) m = fmaxf(m, __shfl_xor(m, o, 16));
      wself = __expf(eself - m);
      float dl = 0.f;
      for (int t0 = 0; t0 < deg; t0 += 16) {
        int j = t0 + l;
        int u2 = 0;
        float w2 = 0.f;
        if (j < deg) {
          u2 = esrc[s + j];
          w2 = __expf(leaky(vas[u2] + adv) - m);
          dl += w2;
        }
        const int cnt = min(16, deg - t0);
        for (int i0 = 0; i0 < cnt; i0 += 4) {
          const int tb = cnt - i0;
          uint4 hb[4];
          float wt[4];
#pragma unroll
          for (int i = 0; i < 4; i++) {
            if (i < tb) {
              int ut = __shfl(u2, (lane & 48) + i0 + i, 64);
              wt[i] = __shfl(w2, (lane & 48) + i0 + i, 64);
              hb[i] = H4[(size_t)ut * 16 + l];
            }
          }
#pragma unroll
          for (int i = 0; i < 4; i++)
            if (i < tb) accum8(acc, wt[i], hb[i]);
        }
      }
      dsum = dl;
#pragma unroll
      for (int o = 8; o; o >>= 1) dsum += __shfl_xor(dsum, o, 16);
    }

    accum8(acc, wself, hs);
    const float inv = 1.0f / (dsum + wself);
    float4 b0 = *(const float4*)&bias[8 * l];
    float4 b1v = *(const float4*)&bias[8 * l + 4];
    acc[0] = acc[0] * inv + b0.x; acc[1] = acc[1] * inv + b0.y;
    acc[2] = acc[2] * inv + b0.z; acc[3] = acc[3] * inv + b0.w;
    acc[4] = acc[4] * inv + b1v.x; acc[5] = acc[5] * inv + b1v.y;
    acc[6] = acc[6] * inv + b1v.z; acc[7] = acc[7] * inv + b1v.w;

    if (LAYER == 1) {
#pragma unroll
      for (int k = 0; k < 8; k++) acc[k] = fmaxf(acc[k], 0.f);
      uint4 o;
      o.x = packbf(acc[0], acc[1]);
      o.y = packbf(acc[2], acc[3]);
      o.z = packbf(acc[4], acc[5]);
      o.w = packbf(acc[6], acc[7]);
      ((uint4*)OutBf)[(size_t)node * 16 + l] = o;
    }
  }

  if (LAYER == 2) {
#pragma unroll
    for (int k = 0; k < 8; k++) {
      acc[k] += __shfl_xor(acc[k], 16, 64);
      acc[k] += __shfl_xor(acc[k], 32, 64);
    }
    __shared__ float red[4][128];
    if (q == 0) {
#pragma unroll
      for (int k = 0; k < 8; k++) red[wv][8 * l + k] = acc[k];
    }
    __syncthreads();
    if (tid < 128) {
      float sm = red[0][tid] + red[1][tid] + red[2][tid] + red[3][tid];
      atomicAdd(&partial[(blockIdx.x & 63) * 128 + tid], sm);
    }
  }
}

// ---------------- finalize: out = sum(partial)/N ----------------
__global__ void finalize_k(const float* __restrict__ partial, float* __restrict__ out,
                           float invn) {
  int c = threadIdx.x;  // 128
  float s = 0.f;
#pragma unroll 8
  for (int r = 0; r < 64; r++) s += partial[r * 128 + c];
  out[c] = s * invn;
}

extern "C" void kernel_launch(void* const* d_in, const int* in_sizes, int n_in,
                              void* d_out, int out_size, void* d_ws, size_t ws_size,
                              hipStream_t stream) {
  const float* x = (const float*)d_in[0];
  const int* ei = (const int*)d_in[1];
  const float* W1 = (const float*)d_in[2];
  const float* a_src1 = (const float*)d_in[3];
  const float* a_dst1 = (const float*)d_in[4];
  const float* b1 = (const float*)d_in[5];
  const float* W2 = (const float*)d_in[6];
  const float* a_src2 = (const float*)d_in[7];
  const float* a_dst2 = (const float*)d_in[8];
  const float* b2 = (const float*)d_in[9];
  float* out = (float*)d_out;

  const int N = in_sizes[0] / 128;
  const int E = in_sizes[1] / 2;
  const int* src = ei;
  const int* dst = ei + E;

  const size_t rowpadded = (size_t)(N + 64) * 128;

  char* p = (char*)d_ws;
  unsigned short* B1h = (unsigned short*)p; p += rowpadded * 2;  // layer-1 agg out (bf16)
  unsigned short* Hh = (unsigned short*)p;  p += rowpadded * 2;  // per-layer GEMM out (bf16)
  float* vas = (float*)p;     p += (size_t)N * 4;
  float* vad = (float*)p;     p += (size_t)N * 4;
  int* deg = (int*)p;         p += (size_t)N * 4;
  int* rowst = (int*)p;       p += (size_t)(N + 1) * 4;
  int* fill = (int*)p;        p += (size_t)N * 4;
  int* esrc = (int*)p;        p += (size_t)E * 4;
  int* exc = (int*)p;         p += (size_t)N * 4;
  int* bsum = (int*)p;        p += 256 * 4;
  float* partial = (float*)p; p += 64 * 128 * 4;
  unsigned short* Wf1 = (unsigned short*)p; p += 16384 * 2;
  unsigned short* Wf2 = (unsigned short*)p; p += 16384 * 2;

  const int nb = (N + 1023) / 1024;  // 98 (<=128 required by scan_c2 reduce)
  const int eblocks = (E + 255) / 256;
  const int nt16 = (N + 15) / 16;
  const int aggblocks = (N + 15) / 16;  // 16 nodes per 256-thread block

  // --- CSR over dst + W prep ---
  hipMemsetAsync(deg, 0, (size_t)N * 4, stream);
  prep_w<<<2, 256, 0, stream>>>(W1, W2, Wf1, Wf2);
  hist_kernel<<<eblocks, 256, 0, stream>>>(dst, deg, E);
  scan_a<<<nb, 256, 0, stream>>>(deg, exc, bsum, N);
  scan_c2<<<nb, 256, 0, stream>>>(exc, bsum, rowst, fill, N, E, nb);
  scatter_kernel<<<eblocks, 256, 0, stream>>>(src, dst, fill, esrc, E);

  // --- layer 1 (fp32 x read directly) ---
  gemm_mfma<true><<<512, 256, 0, stream>>>(x, Wf1, a_src1, a_dst1, Hh, vas, vad, N, nt16);
  gat_agg2<1><<<aggblocks, 256, 0, stream>>>(Hh, vas, vad, rowst, esrc, b1, B1h, nullptr, N);

  // --- layer 2 (fused mean) ---
  gemm_mfma<false><<<512, 256, 0, stream>>>(B1h, Wf2, a_src2, a_dst2, Hh, vas, vad, N, nt16);
  hipMemsetAsync(partial, 0, 64 * 128 * 4, stream);
  gat_agg2<2><<<aggblocks, 256, 0, stream>>>(Hh, vas, vad, rowst, esrc, b2, nullptr, partial, N);

  // --- finalize mean ---
  finalize_k<<<1, 128, 0, stream>>>(partial, out, 1.0f / (float)N);
}

// Round 6
// 304.730 us; speedup vs baseline: 1.0108x; 1.0108x over previous
//
#include <hip/hip_runtime.h>

// PersonaGNN: 2-layer GAT, N=100000, E=600000 (+self loops), dims 128, fp32 io.
//
// R6:
//  - gemm_mfma v4: ONE 16-row tile per wave (grid 1563 blocks -> ~24 waves/CU),
//    no grid-stride loop, no prefetch rotation (R5's rotate forced a vmcnt(0)
//    drain per tile). W frags re-loaded from L2 per ks-step (8 coalesced
//    dwordx4; 64KB Wf is cache-hot) -> ~110 VGPR -> 4 waves/SIMD.
//  - gat_agg2: fast-path feature gathers batched 8-deep (was 4).
//  - Note: 2x 268MB harness ws-poison fills (~80us) are inside the timed
//    window and not addressable; our kernel budget is the remainder.

#define NEG_SLOPE 0.2f

typedef __attribute__((ext_vector_type(8))) short bf16x8;
typedef __attribute__((ext_vector_type(4))) float f32x4;

__device__ __forceinline__ float leaky(float x) { return x > 0.0f ? x : NEG_SLOPE * x; }

__device__ __forceinline__ unsigned int bf16rne(float f) {
  unsigned int u = __float_as_uint(f);
  return (u + 0x7fffu + ((u >> 16) & 1u)) >> 16;
}
__device__ __forceinline__ unsigned int packbf(float a, float b) {
  return bf16rne(a) | (bf16rne(b) << 16);
}
__device__ __forceinline__ float bf_lo(unsigned int u) { return __uint_as_float(u << 16); }
__device__ __forceinline__ float bf_hi(unsigned int u) { return __uint_as_float(u & 0xffff0000u); }

__device__ __forceinline__ void accum8(float* a, float w, uint4 h) {
  a[0] += w * bf_lo(h.x); a[1] += w * bf_hi(h.x);
  a[2] += w * bf_lo(h.y); a[3] += w * bf_hi(h.y);
  a[4] += w * bf_lo(h.z); a[5] += w * bf_hi(h.z);
  a[6] += w * bf_lo(h.w); a[7] += w * bf_hi(h.w);
}

// ---------------- CSR build ----------------
__global__ void hist_kernel(const int* __restrict__ dst, int* __restrict__ deg, int E) {
  int e = blockIdx.x * 256 + threadIdx.x;
  if (e < E) atomicAdd(&deg[dst[e]], 1);
}

__global__ void scan_a(const int* __restrict__ cnt, int* __restrict__ exc,
                       int* __restrict__ bsum, int n) {
  __shared__ int sh[256];
  int b = blockIdx.x, tid = threadIdx.x;
  int base = b * 1024 + tid * 4;
  int v[4];
#pragma unroll
  for (int i = 0; i < 4; i++) v[i] = (base + i < n) ? cnt[base + i] : 0;
  int tsum = v[0] + v[1] + v[2] + v[3];
  sh[tid] = tsum;
  __syncthreads();
  for (int o = 1; o < 256; o <<= 1) {
    int t = (tid >= o) ? sh[tid - o] : 0;
    __syncthreads();
    sh[tid] += t;
    __syncthreads();
  }
  if (tid == 255) bsum[b] = sh[255];
  int run = sh[tid] - tsum;
#pragma unroll
  for (int i = 0; i < 4; i++) {
    if (base + i < n) exc[base + i] = run;
    run += v[i];
  }
}

__global__ void scan_c2(const int* __restrict__ exc, const int* __restrict__ bsum,
                        int* __restrict__ rowst, int* __restrict__ fill, int n, int E,
                        int nb) {
  __shared__ int red[256];
  int b = blockIdx.x, tid = threadIdx.x;
  red[tid] = (tid < b && tid < nb) ? bsum[tid] : 0;
  __syncthreads();
#pragma unroll
  for (int o = 128; o; o >>= 1) {
    if (tid < o) red[tid] += red[tid + o];
    __syncthreads();
  }
  int off = red[0];
  int base = b * 1024 + tid * 4;
#pragma unroll
  for (int i = 0; i < 4; i++) {
    int idx = base + i;
    if (idx < n) {
      int v = exc[idx] + off;
      rowst[idx] = v;
      fill[idx] = v;
    }
  }
  if (b == 0 && tid == 0) rowst[n] = E;
}

__global__ void scatter_kernel(const int* __restrict__ src, const int* __restrict__ dst,
                               int* __restrict__ fill, int* __restrict__ esrc, int E) {
  int e = blockIdx.x * 256 + threadIdx.x;
  if (e < E) {
    int v = dst[e];
    int p = atomicAdd(&fill[v], 1);
    esrc[p] = src[e];
  }
}

// -------- prep_w: pack W (fp32 [k][n]) into fragment-ordered bf16 ----------
// Wf[(ct*4+ks)*512 + lane*8 + j] = bf16(W[ks*32 + (lane>>4)*8 + j][ct*16 + (lane&15)])
__global__ void prep_w(const float* __restrict__ W1, const float* __restrict__ W2,
                       unsigned short* __restrict__ Wf1, unsigned short* __restrict__ Wf2) {
  const float* W = blockIdx.x ? W2 : W1;
  unsigned short* Wf = blockIdx.x ? Wf2 : Wf1;
  for (int idx = threadIdx.x; idx < 16384; idx += 256) {
    int j = idx & 7;
    int lane = (idx >> 3) & 63;
    int fid = idx >> 9;
    int ct = fid >> 2, ks = fid & 3;
    int q = lane >> 4, l15 = lane & 15;
    Wf[idx] = (unsigned short)bf16rne(W[(ks * 32 + q * 8 + j) * 128 + ct * 16 + l15]);
  }
}

// ------- MFMA GEMM v4: H[n,128](bf16) = X[n,128] @ W, + fused dots ----------
// One 16-row tile per wave. No LDS, no barriers, no loops over tiles.
// ks-outer / ct-inner so the first MFMA only depends on xf[0].
template <bool F32IN>
__global__ __launch_bounds__(256, 2) void gemm_mfma(const void* __restrict__ Xin,
                                                    const unsigned short* __restrict__ Wf,
                                                    const float* __restrict__ a_s,
                                                    const float* __restrict__ a_d,
                                                    unsigned short* __restrict__ H,
                                                    float* __restrict__ vas,
                                                    float* __restrict__ vad, int n,
                                                    int nt16) {
  const int lane = threadIdx.x & 63;
  const int wv = threadIdx.x >> 6;
  const int l15 = lane & 15;
  const int q = lane >> 4;
  const int t = blockIdx.x * 4 + wv;
  if (t >= nt16) return;
  const int myrow = t * 16 + l15;
  const bool act = myrow < n;

  // ---- X tile load (issue all loads up front) ----
  bf16x8 xf[4];
  if constexpr (F32IN) {
    const float* __restrict__ Xf = (const float*)Xin;
    float4 raw[8];
#pragma unroll
    for (int ks = 0; ks < 4; ks++) {
      float4 z = {0.f, 0.f, 0.f, 0.f};
      raw[2 * ks] = z;
      raw[2 * ks + 1] = z;
      if (act) {
        raw[2 * ks] = *(const float4*)&Xf[(size_t)myrow * 128 + ks * 32 + q * 8];
        raw[2 * ks + 1] = *(const float4*)&Xf[(size_t)myrow * 128 + ks * 32 + q * 8 + 4];
      }
    }
#pragma unroll
    for (int ks = 0; ks < 4; ks++) {
      union { bf16x8 v; unsigned int u[4]; } cv;
      cv.u[0] = packbf(raw[2 * ks].x, raw[2 * ks].y);
      cv.u[1] = packbf(raw[2 * ks].z, raw[2 * ks].w);
      cv.u[2] = packbf(raw[2 * ks + 1].x, raw[2 * ks + 1].y);
      cv.u[3] = packbf(raw[2 * ks + 1].z, raw[2 * ks + 1].w);
      xf[ks] = cv.v;
    }
  } else {
    const unsigned short* __restrict__ Xh = (const unsigned short*)Xin;  // padded rows
#pragma unroll
    for (int ks = 0; ks < 4; ks++)
      xf[ks] = *(const bf16x8*)&Xh[(size_t)myrow * 128 + ks * 32 + q * 8];
  }

  f32x4 acc[8];
#pragma unroll
  for (int ct = 0; ct < 8; ct++) acc[ct] = (f32x4){0.f, 0.f, 0.f, 0.f};

#pragma unroll
  for (int ks = 0; ks < 4; ks++) {
    bf16x8 wf[8];
#pragma unroll
    for (int ct = 0; ct < 8; ct++)
      wf[ct] = *(const bf16x8*)&Wf[(((ct << 2) + ks) << 9) + lane * 8];
#pragma unroll
    for (int ct = 0; ct < 8; ct++)
      acc[ct] = __builtin_amdgcn_mfma_f32_16x16x32_bf16(wf[ct], xf[ks], acc[ct], 0, 0, 0);
  }

  // ---- epilogue: lane holds H[myrow][ct*16 + q*4 + r], r=0..3 ----
  float ds = 0.f, dd = 0.f;
#pragma unroll
  for (int ct = 0; ct < 8; ct++) {
    const int c0 = ct * 16 + q * 4;
    float4 as4 = *(const float4*)&a_s[c0];
    float4 ad4 = *(const float4*)&a_d[c0];
    ds += acc[ct][0] * as4.x + acc[ct][1] * as4.y + acc[ct][2] * as4.z + acc[ct][3] * as4.w;
    dd += acc[ct][0] * ad4.x + acc[ct][1] * ad4.y + acc[ct][2] * ad4.z + acc[ct][3] * ad4.w;
    if (act) {
      uint2 o;
      o.x = packbf(acc[ct][0], acc[ct][1]);
      o.y = packbf(acc[ct][2], acc[ct][3]);
      *(uint2*)&H[(size_t)myrow * 128 + c0] = o;
    }
  }
  ds += __shfl_xor(ds, 16, 64);
  ds += __shfl_xor(ds, 32, 64);
  dd += __shfl_xor(dd, 16, 64);
  dd += __shfl_xor(dd, 32, 64);
  if (q == 0 && act) {
    vas[myrow] = ds;
    vad[myrow] = dd;
  }
}

// ---------------- GAT aggregation: 4 nodes per wave, 16 lanes/node ----------------
// LAYER==1: relu + bf16 node output.  LAYER==2: fused mean into partial[64][128].
template <int LAYER>
__global__ __launch_bounds__(256) void gat_agg2(const unsigned short* __restrict__ H,
                                                const float* __restrict__ vas,
                                                const float* __restrict__ vad,
                                                const int* __restrict__ rowst,
                                                const int* __restrict__ esrc,
                                                const float* __restrict__ bias,
                                                unsigned short* __restrict__ OutBf,
                                                float* __restrict__ partial, int n) {
  const int tid = threadIdx.x;
  const int lane = tid & 63;
  const int wv = tid >> 6;
  const int q = lane >> 4;
  const int l = lane & 15;
  const int node = (blockIdx.x * 4 + wv) * 4 + q;  // 16 nodes per block
  const uint4* __restrict__ H4 = (const uint4*)H;

  float acc[8];
#pragma unroll
  for (int k = 0; k < 8; k++) acc[k] = 0.f;

  if (node < n) {
    const int s = rowst[node];
    const int e = rowst[node + 1];
    const int deg = e - s;
    const float adv = vad[node];
    const float eself = leaky(vas[node] + adv);
    uint4 hs = H4[(size_t)node * 16 + l];
    float wself, dsum;

    if (deg <= 16) {
      int uj = 0;
      float ej = -1e30f;
      const bool a = l < deg;
      if (a) {
        uj = esrc[s + l];
        ej = leaky(vas[uj] + adv);
      }
      float m = fmaxf(eself, ej);
#pragma unroll
      for (int o = 8; o; o >>= 1) m = fmaxf(m, __shfl_xor(m, o, 16));
      float wj = a ? __expf(ej - m) : 0.f;
      wself = __expf(eself - m);
      dsum = wj;
#pragma unroll
      for (int o = 8; o; o >>= 1) dsum += __shfl_xor(dsum, o, 16);
#pragma unroll 1
      for (int t0 = 0; t0 < deg; t0 += 8) {
        const int tb = deg - t0;  // wave-uniform
        uint4 hb[8];
        float wt[8];
#pragma unroll
        for (int i = 0; i < 8; i++) {
          if (i < tb) {
            int ut = __shfl(uj, (lane & 48) + t0 + i, 64);
            wt[i] = __shfl(wj, (lane & 48) + t0 + i, 64);
            hb[i] = H4[(size_t)ut * 16 + l];
          }
        }
#pragma unroll
        for (int i = 0; i < 8; i++)
          if (i < tb) accum8(acc, wt[i], hb[i]);
      }
    } else {
      // generic (deg>16 is rare)
      float m = eself;
      for (int t0 = 0; t0 < deg; t0 += 16) {
        int j = t0 + l;
        if (j < deg) {
          int u = esrc[s + j];
          m = fmaxf(m, leaky(vas[u] + adv));
        }
      }
#pragma unroll
      for (int o = 8; o; o >>= 1) m = fmaxf(m, __shfl_xor(m, o, 16));
      wself = __expf(eself - m);
      float dl = 0.f;
      for (int t0 = 0; t0 < deg; t0 += 16) {
        int j = t0 + l;
        int u2 = 0;
        float w2 = 0.f;
        if (j < deg) {
          u2 = esrc[s + j];
          w2 = __expf(leaky(vas[u2] + adv) - m);
          dl += w2;
        }
        const int cnt = min(16, deg - t0);
        for (int i0 = 0; i0 < cnt; i0 += 8) {
          const int tb = cnt - i0;
          uint4 hb[8];
          float wt[8];
#pragma unroll
          for (int i = 0; i < 8; i++) {
            if (i < tb) {
              int ut = __shfl(u2, (lane & 48) + i0 + i, 64);
              wt[i] = __shfl(w2, (lane & 48) + i0 + i, 64);
              hb[i] = H4[(size_t)ut * 16 + l];
            }
          }
#pragma unroll
          for (int i = 0; i < 8; i++)
            if (i < tb) accum8(acc, wt[i], hb[i]);
        }
      }
      dsum = dl;
#pragma unroll
      for (int o = 8; o; o >>= 1) dsum += __shfl_xor(dsum, o, 16);
    }

    accum8(acc, wself, hs);
    const float inv = 1.0f / (dsum + wself);
    float4 b0 = *(const float4*)&bias[8 * l];
    float4 b1v = *(const float4*)&bias[8 * l + 4];
    acc[0] = acc[0] * inv + b0.x; acc[1] = acc[1] * inv + b0.y;
    acc[2] = acc[2] * inv + b0.z; acc[3] = acc[3] * inv + b0.w;
    acc[4] = acc[4] * inv + b1v.x; acc[5] = acc[5] * inv + b1v.y;
    acc[6] = acc[6] * inv + b1v.z; acc[7] = acc[7] * inv + b1v.w;

    if (LAYER == 1) {
#pragma unroll
      for (int k = 0; k < 8; k++) acc[k] = fmaxf(acc[k], 0.f);
      uint4 o;
      o.x = packbf(acc[0], acc[1]);
      o.y = packbf(acc[2], acc[3]);
      o.z = packbf(acc[4], acc[5]);
      o.w = packbf(acc[6], acc[7]);
      ((uint4*)OutBf)[(size_t)node * 16 + l] = o;
    }
  }

  if (LAYER == 2) {
#pragma unroll
    for (int k = 0; k < 8; k++) {
      acc[k] += __shfl_xor(acc[k], 16, 64);
      acc[k] += __shfl_xor(acc[k], 32, 64);
    }
    __shared__ float red[4][128];
    if (q == 0) {
#pragma unroll
      for (int k = 0; k < 8; k++) red[wv][8 * l + k] = acc[k];
    }
    __syncthreads();
    if (tid < 128) {
      float sm = red[0][tid] + red[1][tid] + red[2][tid] + red[3][tid];
      atomicAdd(&partial[(blockIdx.x & 63) * 128 + tid], sm);
    }
  }
}

// ---------------- finalize: out = sum(partial)/N ----------------
__global__ void finalize_k(const float* __restrict__ partial, float* __restrict__ out,
                           float invn) {
  int c = threadIdx.x;  // 128
  float s = 0.f;
#pragma unroll 8
  for (int r = 0; r < 64; r++) s += partial[r * 128 + c];
  out[c] = s * invn;
}

extern "C" void kernel_launch(void* const* d_in, const int* in_sizes, int n_in,
                              void* d_out, int out_size, void* d_ws, size_t ws_size,
                              hipStream_t stream) {
  const float* x = (const float*)d_in[0];
  const int* ei = (const int*)d_in[1];
  const float* W1 = (const float*)d_in[2];
  const float* a_src1 = (const float*)d_in[3];
  const float* a_dst1 = (const float*)d_in[4];
  const float* b1 = (const float*)d_in[5];
  const float* W2 = (const float*)d_in[6];
  const float* a_src2 = (const float*)d_in[7];
  const float* a_dst2 = (const float*)d_in[8];
  const float* b2 = (const float*)d_in[9];
  float* out = (float*)d_out;

  const int N = in_sizes[0] / 128;
  const int E = in_sizes[1] / 2;
  const int* src = ei;
  const int* dst = ei + E;

  const size_t rowpadded = (size_t)(N + 64) * 128;

  char* p = (char*)d_ws;
  unsigned short* B1h = (unsigned short*)p; p += rowpadded * 2;  // layer-1 agg out (bf16)
  unsigned short* Hh = (unsigned short*)p;  p += rowpadded * 2;  // per-layer GEMM out (bf16)
  float* vas = (float*)p;     p += (size_t)N * 4;
  float* vad = (float*)p;     p += (size_t)N * 4;
  int* deg = (int*)p;         p += (size_t)N * 4;
  int* rowst = (int*)p;       p += (size_t)(N + 1) * 4;
  int* fill = (int*)p;        p += (size_t)N * 4;
  int* esrc = (int*)p;        p += (size_t)E * 4;
  int* exc = (int*)p;         p += (size_t)N * 4;
  int* bsum = (int*)p;        p += 256 * 4;
  float* partial = (float*)p; p += 64 * 128 * 4;
  unsigned short* Wf1 = (unsigned short*)p; p += 16384 * 2;
  unsigned short* Wf2 = (unsigned short*)p; p += 16384 * 2;

  const int nb = (N + 1023) / 1024;  // 98 (<=128 required by scan_c2 reduce)
  const int eblocks = (E + 255) / 256;
  const int nt16 = (N + 15) / 16;
  const int gemmblocks = (nt16 + 3) / 4;  // 1 tile per wave
  const int aggblocks = (N + 15) / 16;    // 16 nodes per 256-thread block

  // --- CSR over dst + W prep ---
  hipMemsetAsync(deg, 0, (size_t)N * 4, stream);
  prep_w<<<2, 256, 0, stream>>>(W1, W2, Wf1, Wf2);
  hist_kernel<<<eblocks, 256, 0, stream>>>(dst, deg, E);
  scan_a<<<nb, 256, 0, stream>>>(deg, exc, bsum, N);
  scan_c2<<<nb, 256, 0, stream>>>(exc, bsum, rowst, fill, N, E, nb);
  scatter_kernel<<<eblocks, 256, 0, stream>>>(src, dst, fill, esrc, E);

  // --- layer 1 (fp32 x read directly) ---
  gemm_mfma<true><<<gemmblocks, 256, 0, stream>>>(x, Wf1, a_src1, a_dst1, Hh, vas, vad, N, nt16);
  gat_agg2<1><<<aggblocks, 256, 0, stream>>>(Hh, vas, vad, rowst, esrc, b1, B1h, nullptr, N);

  // --- layer 2 (fused mean) ---
  gemm_mfma<false><<<gemmblocks, 256, 0, stream>>>(B1h, Wf2, a_src2, a_dst2, Hh, vas, vad, N, nt16);
  hipMemsetAsync(partial, 0, 64 * 128 * 4, stream);
  gat_agg2<2><<<aggblocks, 256, 0, stream>>>(Hh, vas, vad, rowst, esrc, b2, nullptr, partial, N);

  // --- finalize mean ---
  finalize_k<<<1, 128, 0, stream>>>(partial, out, 1.0f / (float)N);
}